// Round 4
// baseline (506.076 us; speedup 1.0000x reference)
//
#include <hip/hip_runtime.h>
#include <math.h>

#define BS 128
#define GS 2000
#define E  128
#define KMAXI 4
#define CLIPV 10.0f
#define NEGV  -1.0e30f

typedef __bf16 bf16_t;
typedef __bf16 bf16x8 __attribute__((ext_vector_type(8)));
typedef float fx4 __attribute__((ext_vector_type(4)));
typedef float fx2 __attribute__((ext_vector_type(2)));

__device__ __forceinline__ float fast_sigmoid(float x){ return 1.0f/(1.0f+__expf(-x)); }
__device__ __forceinline__ float fast_tanhf(float x){
    float e = __expf(2.0f*x);
    return 1.0f - 2.0f/(e + 1.0f);
}
// Padé(3,2) tanh clamped at |x|=3 — used only in the tiny epilogue (8/leader-lane).
__device__ __forceinline__ float pade_tanh(float x){
    float t = __builtin_amdgcn_fmed3f(x, -3.0f, 3.0f);
    float r = t*t;
    float num = t*(27.0f + r);
    float den = fmaf(9.0f, r, 27.0f);
    return num * __builtin_amdgcn_rcpf(den);
}
// Packed odd-poly tanh, clamp at |x|=3 (max err ~0.036; rcp-free, pk_fma-friendly).
__device__ __forceinline__ fx2 tanh2_poly(fx2 x){
    fx2 t;
    t.x = __builtin_amdgcn_fmed3f(x.x, -3.0f, 3.0f);
    t.y = __builtin_amdgcn_fmed3f(x.y, -3.0f, 3.0f);
    fx2 r = t*t;
    fx2 q = r*(-0.0015650f) + 0.03172875f;
    q = q*r + (-0.23082094f);
    q = q*r + 0.979947f;
    return t*q;
}
// diff known to lie in (-GS, GS): python-mod without integer divide
__device__ __forceinline__ int pymod_s(int a){ return a < 0 ? a + GS : a; }

// global -> LDS direct DMA, 16B per lane. lds per-lane ptr must be base + lane*16 (m97/m104).
__device__ __forceinline__ void load_lds16(const bf16_t* g, bf16_t* l){
    __builtin_amdgcn_global_load_lds(
        (const __attribute__((address_space(1))) void*)g,
        (__attribute__((address_space(3))) void*)l, 16, 0, 0);
}

// scalars layout per b (stride 64 ints): [0]=a0 ; per it at 8+it*8:
// +0 action, +1 old_stopped, +2 new_stopped, +3 allow, +4 vta, +5 row1, +6 row2
#define SC_STRIDE 64

// ---------------------------------------------------------------- h mean partials (+ traj on the extra y-slice)
__global__ __launch_bounds__(256) void k_hmean(
    const float* __restrict__ h, float* __restrict__ hpart,
    const int* __restrict__ rec, const int* __restrict__ vtime,
    const int* __restrict__ last_action, const int* __restrict__ fixed_action,
    int* __restrict__ sc, float* __restrict__ out)
{
    int b = blockIdx.x, p = blockIdx.y, tid = threadIdx.x;
    if (p == 16){
        // integer trajectory: one block (b==0), thread = batch element
        if (b != 0) return;
        int t = tid;
        if (t >= BS) return;
        int stopped = 1, nol = -1;
        int ai[4]={0,0,0,0}, kl[5]={0,0,0,0,0}, kr[4]={0,0,0,0};
        int a0 = 0;
        int* scb = sc + t*SC_STRIDE;
        for (int it=0; it<KMAXI; ++it){
            int action = (it==0) ? fixed_action[t*KMAXI]
                                 : (stopped ? ai[0] : fixed_action[t*KMAXI+it]);
            int old_stopped = stopped;
            if (it==0) a0 = action;
            int vta = (it==0) ? 0 : pymod_s(vtime[(size_t)t*GS+action] - vtime[(size_t)t*GS+a0]);
            int nna = rec[(size_t)t*GS+action];
            int eq  = (action == nol) ? 1 : 0;
            int new_stopped = (it==0) ? eq : (stopped | eq);
            int ai0 = (it==0) ? action : ai[0];
            int allow = (!new_stopped) && (nna == ai0);

            ai[it] = action;
            if (old_stopped)  kl[it] = action;
            if (!old_stopped) kr[(it+3)&3] = action;
            kl[it+1] = nna;
            if (new_stopped) kl[it] = kl[(it+4)%5];
            if (new_stopped) kr[it] = kr[(it+3)&3];

            int row1 = action;
            int i2 = pymod_s(nol);
            int row2 = old_stopped ? row1 : i2;

            int* s_it = scb + 8 + it*8;
            s_it[0]=action; s_it[1]=old_stopped; s_it[2]=new_stopped;
            s_it[3]=allow;  s_it[4]=vta; s_it[5]=row1; s_it[6]=row2;

            nol = new_stopped ? -1 : nna;
            stopped = new_stopped;
        }
        scb[0] = a0;
        if (!stopped) kr[3] = kl[4];
        for (int j=0;j<4;++j) out[t*12+j]   = (float)ai[j];
        for (int j=0;j<4;++j) out[t*12+4+j] = (float)kl[j];
        for (int j=0;j<4;++j) out[t*12+8+j] = (float)kr[j];
        return;
    }
    int e4 = (tid & 31) * 4;
    int gsub = tid >> 5;
    float4 acc = {0.f,0.f,0.f,0.f};
    int g0 = p*125, g1 = g0+125;
    for (int g = g0 + gsub; g < g1; g += 8){
        float4 v = *(const float4*)(h + ((size_t)b*GS + g)*E + e4);
        acc.x += v.x; acc.y += v.y; acc.z += v.z; acc.w += v.w;
    }
    __shared__ float ps[8][E];
    *(float4*)(&ps[gsub][e4]) = acc;
    __syncthreads();
    if (tid < E){
        float s = 0.f;
        #pragma unroll
        for (int j=0;j<8;++j) s += ps[j][tid];
        hpart[(b*16+p)*E + tid] = s;
    }
}

__device__ __forceinline__ float dot32(const float* a, const float* __restrict__ w){
    const float4* a4=(const float4*)a; const float4* w4=(const float4*)w;
    float s=0.f;
    #pragma unroll 8
    for (int i=0;i<32;++i){ float4 x=a4[i], y=w4[i]; s += x.x*y.x + x.y*y.y + x.z*y.z + x.w*y.w; }
    return s;
}

// ---------------------------------------------------------------- all 4 GRU steps, 384 threads:
// one (ih,hh) gate-row pair per thread, then 256 threads for the two projections.
__global__ __launch_bounds__(384) void k_gru4(
    const float* __restrict__ hpart, const float* __restrict__ W_init,
    const float* __restrict__ b_init, const float* __restrict__ init_query,
    const float* __restrict__ h, const int* __restrict__ sc,
    const float* __restrict__ Wih1, const float* __restrict__ Whh1,
    const float* __restrict__ bih1, const float* __restrict__ bhh1,
    const float* __restrict__ Wih2, const float* __restrict__ Whh2,
    const float* __restrict__ bih2, const float* __restrict__ bhh2,
    const float* __restrict__ WQ1, const float* __restrict__ WQ2,
    const float* __restrict__ WQ3, const float* __restrict__ WQ4,
    float* __restrict__ add_buf, float* __restrict__ mul_buf)
{
    int b = blockIdx.x, rnn = blockIdx.y, t = threadIdx.x;
    const float* Wih = rnn ? Wih2 : Wih1;
    const float* Whh = rnn ? Whh2 : Whh1;
    const float* bih = rnn ? bih2 : bih1;
    const float* bhh = rnn ? bhh2 : bhh1;
    const float* WQa = rnn ? WQ2 : WQ1;
    const float* WQm = rnn ? WQ4 : WQ3;

    __shared__ float xv[E], hv[E];
    __shared__ float gi_s[3*E], gh_s[3*E];

    if (t < E){
        float s = 0.f;
        for (int p=0;p<16;++p) s += hpart[(b*16+p)*E + t];
        xv[t] = s * (1.0f/(float)GS);
    }
    __syncthreads();
    if (t < E) hv[t] = b_init[t] + dot32(xv, W_init + (size_t)t*E);
    __syncthreads();
    if (t < E) xv[t] = init_query[t];
    __syncthreads();

    for (int s=0; s<KMAXI; ++s){
        if (s>0){
            if (t < E){
                int row = sc[b*SC_STRIDE + 8 + (s-1)*8 + (rnn==0 ? 5 : 6)];
                xv[t] = h[((size_t)b*GS + row)*E + t];
            }
            __syncthreads();
        }
        // 384 rows: gi[t], gh[t]
        {
            float gi = bih[t] + dot32(xv, Wih + (size_t)t*E);
            float gh = bhh[t] + dot32(hv, Whh + (size_t)t*E);
            gi_s[t] = gi; gh_s[t] = gh;
        }
        __syncthreads();
        if (t < E){
            float r = fast_sigmoid(gi_s[t]     + gh_s[t]);
            float z = fast_sigmoid(gi_s[t+E]   + gh_s[t+E]);
            float n = fast_tanhf  (gi_s[t+2*E] + r*gh_s[t+2*E]);
            hv[t] = (1.f-z)*n + z*hv[t];
        }
        __syncthreads();
        if (t < 2*E){
            int r = t & (E-1);
            const float* W = (t < E) ? WQa : WQm;
            float v = dot32(hv, W + (size_t)r*E);
            int slot = s*2 + rnn;
            if (t < E) add_buf[(size_t)slot*BS*E + b*E + r] = v;
            else       mul_buf[(size_t)slot*BS*E + b*E + r] = v;
        }
        __syncthreads();
    }
}

// ---------------------------------------------------------------- M build, all 8 (it,arm) slots
// Writes SWIZZLED chunk layout: 16B chunk (f,e8) stored at chunk index f*16 + (e8 ^ (f&7)).
// k_scores stages this image linearly via global_load_lds and reads with the same XOR.
__global__ __launch_bounds__(256) void k_mbuild(
    const float* __restrict__ WK1, const float* __restrict__ WK2,
    const float* __restrict__ WK3, const float* __restrict__ WK4,
    const float* __restrict__ mul_buf, bf16_t* __restrict__ Mb)
{
    int b = blockIdx.x, slot = blockIdx.y, tid = threadIdx.x;
    int arm = slot & 1;
    const float* WKa = arm ? WK2 : WK1;
    const float* WKm = arm ? WK4 : WK3;
    const float* mul = mul_buf + (size_t)slot*BS*E + b*E;
    __shared__ float mv[E];
    if (tid < E) mv[tid] = mul[tid];
    __syncthreads();
    bf16x8* outp = (bf16x8*)(Mb + ((size_t)slot*BS + b)*E*E);
    #pragma unroll
    for (int j=0;j<8;++j){
        int u = j*256 + tid;          // chunk id 0..2047
        int f = u >> 4, e8 = u & 15;
        int e0 = e8*8;
        float mf = mv[f];
        float4 a0 = *(const float4*)(WKa + (size_t)f*E + e0);
        float4 a1 = *(const float4*)(WKa + (size_t)f*E + e0 + 4);
        float4 m0 = *(const float4*)(WKm + (size_t)f*E + e0);
        float4 m1 = *(const float4*)(WKm + (size_t)f*E + e0 + 4);
        bf16x8 o;
        o[0]=(bf16_t)(a0.x + m0.x*mf);
        o[1]=(bf16_t)(a0.y + m0.y*mf);
        o[2]=(bf16_t)(a0.z + m0.z*mf);
        o[3]=(bf16_t)(a0.w + m0.w*mf);
        o[4]=(bf16_t)(a1.x + m1.x*mf);
        o[5]=(bf16_t)(a1.y + m1.y*mf);
        o[6]=(bf16_t)(a1.z + m1.z*mf);
        o[7]=(bf16_t)(a1.w + m1.w*mf);
        outp[f*16 + (e8 ^ (f&7))] = o;
    }
}

// ---------------------------------------------------------------- scores + zero-barrier fused masked-LSE partials
// Slot structure reverted to r2 (proven 132.6 us): single 32KB buffer, barrier -> DMA -> barrier -> compute.
// Epilogue: NO extra barriers — each (wave,qd) leader writes its own (max, expsum) partial to global.
__global__ __launch_bounds__(256,2) void k_scores(
    const float* __restrict__ hf, const bf16_t* __restrict__ Mb,
    const float* __restrict__ add_buf,
    const float* __restrict__ V1, const float* __restrict__ V2,
    const int* __restrict__ vtime, const int* __restrict__ last_action,
    const int* __restrict__ sc,
    float* __restrict__ part, float* __restrict__ act_val)
{
    __shared__ bf16_t sM[E*E];       // 32768 B, linear DMA image (swizzled at source)
    int b = blockIdx.x, yc = blockIdx.y, tid = threadIdx.x;
    int wave = tid >> 6, lane = tid & 63;
    int qd = lane >> 4, cl = lane & 15;
    int gbase = yc*128 + wave*32;

    // traj uniforms for the fused LSE
    const int* scb = sc + b*SC_STRIDE;
    int a0s = scb[0];
    int la  = last_action[b];
    int vt0 = vtime[(size_t)b*GS + a0s];

    // V preload (per kernel): vv_r[arm][tf] = V[tf*16+cl]
    float vv_r[2][8];
    #pragma unroll
    for (int tf=0; tf<8; ++tf){
        vv_r[0][tf] = V1[tf*16+cl];
        vv_r[1][tf] = V2[tf*16+cl];
    }

    // A fragments: 2 sets x 16 g-rows, K=128 (32 VGPRs)
    bf16x8 afr[2][4];
    #pragma unroll
    for (int set=0; set<2; ++set){
        int grow = gbase + set*16 + cl;
        if (grow >= GS) grow = GS-1;
        const float* hrow = hf + ((size_t)b*GS + grow)*E;
        #pragma unroll
        for (int s=0;s<4;++s){
            const float* p = hrow + s*32 + qd*8;
            float4 u0 = *(const float4*)(p);
            float4 u1 = *(const float4*)(p+4);
            bf16x8 a;
            a[0]=(bf16_t)u0.x; a[1]=(bf16_t)u0.y; a[2]=(bf16_t)u0.z; a[3]=(bf16_t)u0.w;
            a[4]=(bf16_t)u1.x; a[5]=(bf16_t)u1.y; a[6]=(bf16_t)u1.z; a[7]=(bf16_t)u1.w;
            afr[set][s]=a;
        }
    }

    for (int it=0; it<KMAXI; ++it){
        fx2 s00={0.f,0.f}, s01={0.f,0.f}, s10={0.f,0.f}, s11={0.f,0.f};
        #pragma unroll
        for (int arm=0; arm<2; ++arm){
            int slot = it*2 + arm;
            const bf16_t* Gm = Mb + ((size_t)slot*BS + b)*E*E;
            const float* addv = add_buf + (size_t)slot*BS*E + b*E;

            // per-slot add preload (overlaps barrier+DMA latency)
            float av_r[8];
            #pragma unroll
            for (int tf=0; tf<8; ++tf) av_r[tf] = addv[tf*16+cl];

            __syncthreads();        // previous slot's sM reads complete
            // DMA stage: 8 x 1KB per wave, linear chunks (c = wave*512 + j*64 + lane)
            #pragma unroll
            for (int j=0;j<8;++j){
                int c = wave*512 + j*64 + lane;
                load_lds16(Gm + (size_t)c*8, sM + (size_t)c*8);
            }
            __syncthreads();        // vmcnt(0) drained by compiler before barrier

            #pragma unroll
            for (int tf=0; tf<8; ++tf){
                int f = tf*16 + cl;
                bf16x8 b1[4];
                #pragma unroll
                for (int s=0;s<4;++s){
                    int e8 = s*4 + qd;
                    b1[s] = *(const bf16x8*)(sM + ((size_t)(f*16 + (e8 ^ (f&7))))*8);
                }
                float av = av_r[tf];
                // fold add[f] into the accumulator init (C layout: col=f for all 4 regs)
                fx4 a0 = {av,av,av,av};
                fx4 a1 = {av,av,av,av};
                #pragma unroll
                for (int s=0;s<4;++s){
                    a0 = __builtin_amdgcn_mfma_f32_16x16x32_bf16(afr[0][s], b1[s], a0, 0,0,0);
                    a1 = __builtin_amdgcn_mfma_f32_16x16x32_bf16(afr[1][s], b1[s], a1, 0,0,0);
                }
                fx2 vv2 = {vv_r[arm][tf], vv_r[arm][tf]};
                s00 += vv2 * tanh2_poly((fx2){a0[0], a0[1]});
                s01 += vv2 * tanh2_poly((fx2){a0[2], a0[3]});
                s10 += vv2 * tanh2_poly((fx2){a1[0], a1[1]});
                s11 += vv2 * tanh2_poly((fx2){a1[2], a1[3]});
            }
        }

        // shuffle-reduce -> vfin[set][r] (valid on all 16 lanes of each (wave,qd) group)
        float vfin[2][4];
        #pragma unroll
        for (int set=0;set<2;++set){
            fx2 pa = set ? s10 : s00;
            fx2 pb = set ? s11 : s01;
            float v[4] = {pa.x, pa.y, pb.x, pb.y};
            #pragma unroll
            for (int r=0;r<4;++r){
                float s = v[r];
                s += __shfl_xor(s, 1); s += __shfl_xor(s, 2);
                s += __shfl_xor(s, 4); s += __shfl_xor(s, 8);
                vfin[set][r] = s;
            }
        }

        // zero-barrier masked-LSE partial: each (wave,qd) leader owns 8 rows
        int act = scb[8 + it*8 + 0];
        int ap=0, nsp=0, alp=0, vtp=0;
        if (it>0){
            const int* s_p = scb + 8 + (it-1)*8;
            ap = s_p[0]; nsp = s_p[2]; alp = s_p[3]; vtp = s_p[4];
        }
        if (cl==0){
            float x[8];
            float lm = NEGV;
            #pragma unroll
            for (int set=0;set<2;++set){
                #pragma unroll
                for (int r=0;r<4;++r){
                    int idx = set*4 + r;
                    int g = gbase + set*16 + qd*4 + r;
                    float o = CLIPV*pade_tanh(vfin[set][r]);
                    int valid = (g < GS);
                    int gi = valid ? g : (GS-1);
                    int msk;
                    if (it==0){
                        msk = (g==la);
                    } else {
                        int d = vtime[(size_t)b*GS + gi] - vt0;
                        if (d < 0) d += GS;
                        msk = (d <= vtp) ? 1 : 0;
                        if (it==1 && d > GS-2) msk = 1;
                        if (nsp && g==ap)      msk = 0;
                        if (alp && g==a0s)     msk = 0;
                    }
                    float xx = (valid && !msk) ? o : NEGV;
                    if (valid && g==act) act_val[(size_t)it*BS + b] = xx;
                    x[idx] = xx;
                    lm = fmaxf(lm, xx);
                }
            }
            float ls = 0.f;
            #pragma unroll
            for (int i=0;i<8;++i) ls += __expf(x[i]-lm);
            int pi = yc*16 + wave*4 + qd;         // 0..255 per (b,it)
            fx2 pr = {lm, ls};
            *(fx2*)(part + (((size_t)it*BS + b)*256 + pi)*2) = pr;
        }
        // no barrier here: next it's first slot begins with __syncthreads()
    }
}

// ---------------------------------------------------------------- finalize: combine 256 LSE partials per (b,it)
__global__ __launch_bounds__(512) void k_final(
    const float* __restrict__ part, const float* __restrict__ act_val,
    const int* __restrict__ sc, float* __restrict__ out)
{
    __shared__ float lses[KMAXI][BS];
    int t = threadIdx.x;
    int it = t >> 7, b = t & 127;
    {
        const fx2* pp = (const fx2*)part + ((size_t)it*BS + b)*256;
        float M = NEGV;
        #pragma unroll 8
        for (int i=0;i<256;++i) M = fmaxf(M, pp[i].x);
        float S = 0.f;
        #pragma unroll 8
        for (int i=0;i<256;++i){ fx2 p = pp[i]; S += p.y * __expf(p.x - M); }
        lses[it][b] = M + __logf(S);
    }
    __syncthreads();
    if (t < BS){
        int b2 = t;
        const int* scb = sc + b2*SC_STRIDE;
        float ll = 0.f;
        #pragma unroll
        for (int i2=0; i2<KMAXI; ++i2){
            int olds = scb[8 + i2*8 + 1];
            float loss = act_val[(size_t)i2*BS + b2] - lses[i2][b2];
            if (i2==0 || !olds) ll += loss;
        }
        out[BS*12 + b2] = ll;
    }
}

// ----------------------------------------------------------------
extern "C" void kernel_launch(void* const* d_in, const int* in_sizes, int n_in,
                              void* d_out, int out_size, void* d_ws, size_t ws_size,
                              hipStream_t stream)
{
    const float* h            = (const float*)d_in[0];
    const int*   rec          = (const int*)  d_in[1];
    /* d_in[2] = context2, unused by reference */
    const int*   vtime        = (const int*)  d_in[3];
    const int*   last_action  = (const int*)  d_in[4];
    const int*   fixed_action = (const int*)  d_in[5];
    const float* WK1=(const float*)d_in[6],  *WK2=(const float*)d_in[7];
    const float* WK3=(const float*)d_in[8],  *WK4=(const float*)d_in[9];
    const float* WQ1=(const float*)d_in[10], *WQ2=(const float*)d_in[11];
    const float* WQ3=(const float*)d_in[12], *WQ4=(const float*)d_in[13];
    const float* W_init=(const float*)d_in[14];
    const float* b_init=(const float*)d_in[15];
    const float* V1=(const float*)d_in[16], *V2=(const float*)d_in[17];
    const float* init_query=(const float*)d_in[18];
    const float* Wih1=(const float*)d_in[19], *Whh1=(const float*)d_in[20];
    const float* bih1=(const float*)d_in[21], *bhh1=(const float*)d_in[22];
    const float* Wih2=(const float*)d_in[23], *Whh2=(const float*)d_in[24];
    const float* bih2=(const float*)d_in[25], *bhh2=(const float*)d_in[26];
    float* out = (float*)d_out;

    char* ws = (char*)d_ws;
    size_t off = 0;
    auto alloc = [&](size_t bytes)->char*{
        char* p = ws + off; off += (bytes + 255) & ~(size_t)255; return p;
    };
    bf16_t* Mb     = (bf16_t*)alloc((size_t)8*BS*E*E*sizeof(bf16_t));   // 33.5 MB
    float*  add_buf= (float*) alloc((size_t)8*BS*E*sizeof(float));
    float*  mul_buf= (float*) alloc((size_t)8*BS*E*sizeof(float));
    float*  hpart  = (float*) alloc((size_t)BS*16*E*sizeof(float));
    int*    sc     = (int*)   alloc((size_t)BS*SC_STRIDE*sizeof(int));
    float*  part   = (float*) alloc((size_t)KMAXI*BS*256*2*sizeof(float)); // 1 MB
    float*  actv   = (float*) alloc((size_t)KMAXI*BS*sizeof(float));       // 2 KB
    (void)in_sizes; (void)n_in; (void)out_size; (void)ws_size;

    hipLaunchKernelGGL(k_hmean, dim3(BS,17), dim3(256), 0, stream,
                       h, hpart, rec, vtime, last_action, fixed_action, sc, out);
    hipLaunchKernelGGL(k_gru4, dim3(BS,2), dim3(384), 0, stream,
                       hpart, W_init, b_init, init_query, h, sc,
                       Wih1,Whh1,bih1,bhh1, Wih2,Whh2,bih2,bhh2,
                       WQ1,WQ2,WQ3,WQ4, add_buf, mul_buf);
    hipLaunchKernelGGL(k_mbuild, dim3(BS,8), dim3(256), 0, stream,
                       WK1,WK2,WK3,WK4, mul_buf, Mb);
    hipLaunchKernelGGL(k_scores, dim3(BS,16), dim3(256), 0, stream,
                       h, Mb, add_buf, V1, V2, vtime, last_action, sc, part, actv);
    hipLaunchKernelGGL(k_final, dim3(1), dim3(512), 0, stream,
                       part, actv, sc, out);
}

// Round 5
// 461.736 us; speedup vs baseline: 1.0960x; 1.0960x over previous
//
#include <hip/hip_runtime.h>
#include <math.h>

#define BS 128
#define GS 2000
#define E  128
#define KMAXI 4
#define CLIPV 10.0f
#define NEGV  -1.0e30f

typedef __bf16 bf16_t;
typedef __bf16 bf16x8 __attribute__((ext_vector_type(8)));
typedef float fx4 __attribute__((ext_vector_type(4)));
typedef float fx2 __attribute__((ext_vector_type(2)));

__device__ __forceinline__ float fast_sigmoid(float x){ return 1.0f/(1.0f+__expf(-x)); }
__device__ __forceinline__ float fast_tanhf(float x){
    float e = __expf(2.0f*x);
    return 1.0f - 2.0f/(e + 1.0f);
}
// Padé(3,2) tanh clamped at |x|=3 — epilogue only.
__device__ __forceinline__ float pade_tanh(float x){
    float t = __builtin_amdgcn_fmed3f(x, -3.0f, 3.0f);
    float r = t*t;
    float num = t*(27.0f + r);
    float den = fmaf(9.0f, r, 27.0f);
    return num * __builtin_amdgcn_rcpf(den);
}
// Packed odd-poly tanh, clamp at |x|=3 (max err ~0.036; rcp-free, pk_fma-friendly).
__device__ __forceinline__ fx2 tanh2_poly(fx2 x){
    fx2 t;
    t.x = __builtin_amdgcn_fmed3f(x.x, -3.0f, 3.0f);
    t.y = __builtin_amdgcn_fmed3f(x.y, -3.0f, 3.0f);
    fx2 r = t*t;
    fx2 q = r*(-0.0015650f) + 0.03172875f;
    q = q*r + (-0.23082094f);
    q = q*r + 0.979947f;
    return t*q;
}
// diff known to lie in (-GS, GS): python-mod without integer divide
__device__ __forceinline__ int pymod_s(int a){ return a < 0 ? a + GS : a; }

// global -> LDS direct DMA, 16B per lane. lds dest must be base + lane*16 (m97/m104).
__device__ __forceinline__ void load_lds16(const bf16_t* g, bf16_t* l){
    __builtin_amdgcn_global_load_lds(
        (const __attribute__((address_space(1))) void*)g,
        (__attribute__((address_space(3))) void*)l, 16, 0, 0);
}

// scalars layout per b (stride 64 ints): [0]=a0 ; per it at 8+it*8:
// +0 action, +1 old_stopped, +2 new_stopped, +3 allow, +4 vta, +5 row1, +6 row2
#define SC_STRIDE 64

// ---------------------------------------------------------------- h mean partials (+ traj on the extra y-slice)
__global__ __launch_bounds__(256) void k_hmean(
    const float* __restrict__ h, float* __restrict__ hpart,
    const int* __restrict__ rec, const int* __restrict__ vtime,
    const int* __restrict__ last_action, const int* __restrict__ fixed_action,
    int* __restrict__ sc, float* __restrict__ out)
{
    int b = blockIdx.x, p = blockIdx.y, tid = threadIdx.x;
    if (p == 16){
        // integer trajectory: one block (b==0), thread = batch element
        if (b != 0) return;
        int t = tid;
        if (t >= BS) return;
        int stopped = 1, nol = -1;
        int ai[4]={0,0,0,0}, kl[5]={0,0,0,0,0}, kr[4]={0,0,0,0};
        int a0 = 0;
        int* scb = sc + t*SC_STRIDE;
        for (int it=0; it<KMAXI; ++it){
            int action = (it==0) ? fixed_action[t*KMAXI]
                                 : (stopped ? ai[0] : fixed_action[t*KMAXI+it]);
            int old_stopped = stopped;
            if (it==0) a0 = action;
            int vta = (it==0) ? 0 : pymod_s(vtime[(size_t)t*GS+action] - vtime[(size_t)t*GS+a0]);
            int nna = rec[(size_t)t*GS+action];
            int eq  = (action == nol) ? 1 : 0;
            int new_stopped = (it==0) ? eq : (stopped | eq);
            int ai0 = (it==0) ? action : ai[0];
            int allow = (!new_stopped) && (nna == ai0);

            ai[it] = action;
            if (old_stopped)  kl[it] = action;
            if (!old_stopped) kr[(it+3)&3] = action;
            kl[it+1] = nna;
            if (new_stopped) kl[it] = kl[(it+4)%5];
            if (new_stopped) kr[it] = kr[(it+3)&3];

            int row1 = action;
            int i2 = pymod_s(nol);
            int row2 = old_stopped ? row1 : i2;

            int* s_it = scb + 8 + it*8;
            s_it[0]=action; s_it[1]=old_stopped; s_it[2]=new_stopped;
            s_it[3]=allow;  s_it[4]=vta; s_it[5]=row1; s_it[6]=row2;

            nol = new_stopped ? -1 : nna;
            stopped = new_stopped;
        }
        scb[0] = a0;
        if (!stopped) kr[3] = kl[4];
        out[BS*12 + t] = 0.0f;   // zero ll slot; k_ll atomicAdds later in-stream
        for (int j=0;j<4;++j) out[t*12+j]   = (float)ai[j];
        for (int j=0;j<4;++j) out[t*12+4+j] = (float)kl[j];
        for (int j=0;j<4;++j) out[t*12+8+j] = (float)kr[j];
        return;
    }
    int e4 = (tid & 31) * 4;
    int gsub = tid >> 5;
    float4 acc = {0.f,0.f,0.f,0.f};
    int g0 = p*125, g1 = g0+125;
    for (int g = g0 + gsub; g < g1; g += 8){
        float4 v = *(const float4*)(h + ((size_t)b*GS + g)*E + e4);
        acc.x += v.x; acc.y += v.y; acc.z += v.z; acc.w += v.w;
    }
    __shared__ float ps[8][E];
    *(float4*)(&ps[gsub][e4]) = acc;
    __syncthreads();
    if (tid < E){
        float s = 0.f;
        #pragma unroll
        for (int j=0;j<8;++j) s += ps[j][tid];
        hpart[(b*16+p)*E + tid] = s;
    }
}

__device__ __forceinline__ float dot32(const float* a, const float* __restrict__ w){
    const float4* a4=(const float4*)a; const float4* w4=(const float4*)w;
    float s=0.f;
    #pragma unroll 8
    for (int i=0;i<32;++i){ float4 x=a4[i], y=w4[i]; s += x.x*y.x + x.y*y.y + x.z*y.z + x.w*y.w; }
    return s;
}

// ---------------------------------------------------------------- all 4 GRU steps + fused M-build.
// 384 threads: one (ih,hh) gate-row pair per thread; 256 threads for the two projections;
// then all 384 build M[slot=s*2+rnn] from shared mv (kills k_mbuild + mul_buf).
__global__ __launch_bounds__(384) void k_gru4(
    const float* __restrict__ hpart, const float* __restrict__ W_init,
    const float* __restrict__ b_init, const float* __restrict__ init_query,
    const float* __restrict__ h, const int* __restrict__ sc,
    const float* __restrict__ Wih1, const float* __restrict__ Whh1,
    const float* __restrict__ bih1, const float* __restrict__ bhh1,
    const float* __restrict__ Wih2, const float* __restrict__ Whh2,
    const float* __restrict__ bih2, const float* __restrict__ bhh2,
    const float* __restrict__ WQ1, const float* __restrict__ WQ2,
    const float* __restrict__ WQ3, const float* __restrict__ WQ4,
    const float* __restrict__ WK1, const float* __restrict__ WK2,
    const float* __restrict__ WK3, const float* __restrict__ WK4,
    float* __restrict__ add_buf, bf16_t* __restrict__ Mb)
{
    int b = blockIdx.x, rnn = blockIdx.y, t = threadIdx.x;
    const float* Wih = rnn ? Wih2 : Wih1;
    const float* Whh = rnn ? Whh2 : Whh1;
    const float* bih = rnn ? bih2 : bih1;
    const float* bhh = rnn ? bhh2 : bhh1;
    const float* WQa = rnn ? WQ2 : WQ1;
    const float* WQm = rnn ? WQ4 : WQ3;
    const float* WKa = rnn ? WK2 : WK1;
    const float* WKm = rnn ? WK4 : WK3;

    __shared__ float xv[E], hv[E], mv[E];
    __shared__ float gi_s[3*E], gh_s[3*E];

    if (t < E){
        float s = 0.f;
        for (int p=0;p<16;++p) s += hpart[(b*16+p)*E + t];
        xv[t] = s * (1.0f/(float)GS);
    }
    __syncthreads();
    if (t < E) hv[t] = b_init[t] + dot32(xv, W_init + (size_t)t*E);
    __syncthreads();
    if (t < E) xv[t] = init_query[t];
    __syncthreads();

    for (int s=0; s<KMAXI; ++s){
        if (s>0){
            if (t < E){
                int row = sc[b*SC_STRIDE + 8 + (s-1)*8 + (rnn==0 ? 5 : 6)];
                xv[t] = h[((size_t)b*GS + row)*E + t];
            }
            __syncthreads();
        }
        // 384 rows: gi[t], gh[t]
        {
            float gi = bih[t] + dot32(xv, Wih + (size_t)t*E);
            float gh = bhh[t] + dot32(hv, Whh + (size_t)t*E);
            gi_s[t] = gi; gh_s[t] = gh;
        }
        __syncthreads();
        if (t < E){
            float r = fast_sigmoid(gi_s[t]     + gh_s[t]);
            float z = fast_sigmoid(gi_s[t+E]   + gh_s[t+E]);
            float n = fast_tanhf  (gi_s[t+2*E] + r*gh_s[t+2*E]);
            hv[t] = (1.f-z)*n + z*hv[t];
        }
        __syncthreads();
        int slot = s*2 + rnn;
        if (t < 2*E){
            int r = t & (E-1);
            const float* W = (t < E) ? WQa : WQm;
            float v = dot32(hv, W + (size_t)r*E);
            if (t < E) add_buf[(size_t)slot*BS*E + b*E + r] = v;
            else       mv[r] = v;
        }
        __syncthreads();
        // fused M-build: swizzled chunk layout (f,e8) -> chunk f*16 + (e8^(f&7))
        {
            bf16x8* outp = (bf16x8*)(Mb + ((size_t)slot*BS + b)*E*E);
            for (int u = t; u < 2048; u += 384){
                int f = u >> 4, e8 = u & 15;
                int e0 = e8*8;
                float mf = mv[f];
                float4 a0 = *(const float4*)(WKa + (size_t)f*E + e0);
                float4 a1 = *(const float4*)(WKa + (size_t)f*E + e0 + 4);
                float4 m0 = *(const float4*)(WKm + (size_t)f*E + e0);
                float4 m1 = *(const float4*)(WKm + (size_t)f*E + e0 + 4);
                bf16x8 o;
                o[0]=(bf16_t)(a0.x + m0.x*mf);
                o[1]=(bf16_t)(a0.y + m0.y*mf);
                o[2]=(bf16_t)(a0.z + m0.z*mf);
                o[3]=(bf16_t)(a0.w + m0.w*mf);
                o[4]=(bf16_t)(a1.x + m1.x*mf);
                o[5]=(bf16_t)(a1.y + m1.y*mf);
                o[6]=(bf16_t)(a1.z + m1.z*mf);
                o[7]=(bf16_t)(a1.w + m1.w*mf);
                outp[f*16 + (e8 ^ (f&7))] = o;
            }
        }
        __syncthreads();   // mv consumed before next step's projection rewrites it
    }
}

// ---------------------------------------------------------------- scores: 256-row tile (4 sets), r2 slot structure
// Halves M staging traffic + barrier drains per FLOP. No forced occupancy min (r1: ,4 caused 146MB spill).
__global__ __launch_bounds__(256) void k_scores(
    const float* __restrict__ hf, const bf16_t* __restrict__ Mb,
    const float* __restrict__ add_buf,
    const float* __restrict__ V1, const float* __restrict__ V2,
    float* __restrict__ raw4)
{
    __shared__ bf16_t sM[E*E];       // 32768 B, linear DMA image (swizzled at source)
    int b = blockIdx.x, yc = blockIdx.y, tid = threadIdx.x;
    int wave = tid >> 6, lane = tid & 63;
    int qd = lane >> 4, cl = lane & 15;
    int gbase = yc*256 + wave*64;

    // V preload (per kernel): vv_r[arm][tf] = V[tf*16+cl]
    float vv_r[2][8];
    #pragma unroll
    for (int tf=0; tf<8; ++tf){
        vv_r[0][tf] = V1[tf*16+cl];
        vv_r[1][tf] = V2[tf*16+cl];
    }

    // A fragments: 4 sets x 16 g-rows, K=128 (64 VGPRs)
    bf16x8 afr[4][4];
    #pragma unroll
    for (int set=0; set<4; ++set){
        int grow = gbase + set*16 + cl;
        if (grow >= GS) grow = GS-1;
        const float* hrow = hf + ((size_t)b*GS + grow)*E;
        #pragma unroll
        for (int s=0;s<4;++s){
            const float* p = hrow + s*32 + qd*8;
            float4 u0 = *(const float4*)(p);
            float4 u1 = *(const float4*)(p+4);
            bf16x8 a;
            a[0]=(bf16_t)u0.x; a[1]=(bf16_t)u0.y; a[2]=(bf16_t)u0.z; a[3]=(bf16_t)u0.w;
            a[4]=(bf16_t)u1.x; a[5]=(bf16_t)u1.y; a[6]=(bf16_t)u1.z; a[7]=(bf16_t)u1.w;
            afr[set][s]=a;
        }
    }

    for (int it=0; it<KMAXI; ++it){
        // packed accumulators: acc[set][row-pair]
        fx2 acc[4][2];
        #pragma unroll
        for (int set=0;set<4;++set){ acc[set][0]=(fx2){0.f,0.f}; acc[set][1]=(fx2){0.f,0.f}; }
        #pragma unroll
        for (int arm=0; arm<2; ++arm){
            int slot = it*2 + arm;
            const bf16_t* Gm = Mb + ((size_t)slot*BS + b)*E*E;
            const float* addv = add_buf + (size_t)slot*BS*E + b*E;

            // per-slot add preload (overlaps barrier+DMA latency)
            float av_r[8];
            #pragma unroll
            for (int tf=0; tf<8; ++tf) av_r[tf] = addv[tf*16+cl];

            __syncthreads();        // previous slot's sM reads complete
            // DMA stage: 8 x 1KB per wave, linear chunks (c = wave*512 + j*64 + lane)
            #pragma unroll
            for (int j=0;j<8;++j){
                int c = wave*512 + j*64 + lane;
                load_lds16(Gm + (size_t)c*8, sM + (size_t)c*8);
            }
            __syncthreads();        // vmcnt(0) drained by compiler before barrier

            #pragma unroll
            for (int tf=0; tf<8; ++tf){
                int f = tf*16 + cl;
                bf16x8 b1[4];
                #pragma unroll
                for (int s=0;s<4;++s){
                    int e8 = s*4 + qd;
                    b1[s] = *(const bf16x8*)(sM + ((size_t)(f*16 + (e8 ^ (f&7))))*8);
                }
                float av = av_r[tf];
                // fold add[f] into the accumulator init (C layout: col=f for all 4 regs)
                fx4 a0 = {av,av,av,av};
                fx4 a1 = {av,av,av,av};
                fx4 a2 = {av,av,av,av};
                fx4 a3 = {av,av,av,av};
                #pragma unroll
                for (int s=0;s<4;++s){
                    a0 = __builtin_amdgcn_mfma_f32_16x16x32_bf16(afr[0][s], b1[s], a0, 0,0,0);
                    a1 = __builtin_amdgcn_mfma_f32_16x16x32_bf16(afr[1][s], b1[s], a1, 0,0,0);
                    a2 = __builtin_amdgcn_mfma_f32_16x16x32_bf16(afr[2][s], b1[s], a2, 0,0,0);
                    a3 = __builtin_amdgcn_mfma_f32_16x16x32_bf16(afr[3][s], b1[s], a3, 0,0,0);
                }
                fx2 vv2 = {vv_r[arm][tf], vv_r[arm][tf]};
                acc[0][0] += vv2 * tanh2_poly((fx2){a0[0], a0[1]});
                acc[0][1] += vv2 * tanh2_poly((fx2){a0[2], a0[3]});
                acc[1][0] += vv2 * tanh2_poly((fx2){a1[0], a1[1]});
                acc[1][1] += vv2 * tanh2_poly((fx2){a1[2], a1[3]});
                acc[2][0] += vv2 * tanh2_poly((fx2){a2[0], a2[1]});
                acc[2][1] += vv2 * tanh2_poly((fx2){a2[2], a2[3]});
                acc[3][0] += vv2 * tanh2_poly((fx2){a3[0], a3[1]});
                acc[3][1] += vv2 * tanh2_poly((fx2){a3[2], a3[3]});
            }
        }
        #pragma unroll
        for (int set=0;set<4;++set){
            fx2 pa = acc[set][0];
            fx2 pb = acc[set][1];
            float v[4] = {pa.x, pa.y, pb.x, pb.y};
            #pragma unroll
            for (int r=0;r<4;++r){
                float s = v[r];
                s += __shfl_xor(s, 1); s += __shfl_xor(s, 2);
                s += __shfl_xor(s, 4); s += __shfl_xor(s, 8);
                v[r] = s;
            }
            if (cl==0){
                int gi = gbase + set*16 + qd*4;
                if (gi+3 < GS){
                    float4 o;
                    o.x = CLIPV*pade_tanh(v[0]);
                    o.y = CLIPV*pade_tanh(v[1]);
                    o.z = CLIPV*pade_tanh(v[2]);
                    o.w = CLIPV*pade_tanh(v[3]);
                    *(float4*)(raw4 + ((size_t)it*BS + b)*GS + gi) = o;
                }
            }
        }
    }
}

// ---------------------------------------------------------------- ll: masked logsumexp, one (b,it) per block (r2-proven)
__global__ __launch_bounds__(256) void k_ll(
    const float* __restrict__ raw4, const int* __restrict__ sc,
    const int* __restrict__ vtime, const int* __restrict__ last_action,
    float* __restrict__ out)
{
    __shared__ float sL[GS];
    __shared__ float red[256];
    int b = blockIdx.x, it = blockIdx.y, t = threadIdx.x;
    const int* scb = sc + b*SC_STRIDE;
    const int* s_it = scb + 8 + it*8;
    int action = s_it[0], olds = s_it[1];
    if (it>0 && olds) return;          // contribution is exactly 0 — uniform per block
    int a0 = scb[0];
    int la = last_action[b];
    int vt0 = vtime[(size_t)b*GS + a0];
    int ap=0, nsp=0, alp=0, vtp=0, p = it-1;
    if (it>0){
        const int* s_p = scb + 8 + p*8;
        ap = s_p[0]; nsp = s_p[2]; alp = s_p[3]; vtp = s_p[4];
    }
    for (int g=t; g<GS; g+=256){
        float l = raw4[((size_t)it*BS + b)*GS + g];
        int m;
        if (it==0){
            m = (g==la);
        } else {
            int d = vtime[(size_t)b*GS+g] - vt0;
            if (d < 0) d += GS;
            m = (d <= vtp) ? 1 : 0;
            if (p==0 && d > GS-2) m = 1;
            if (nsp && g==ap)     m = 0;
            if (alp && g==a0)     m = 0;
        }
        sL[g] = m ? NEGV : l;
    }
    __syncthreads();
    float mx = -3.0e38f;
    for (int g=t; g<GS; g+=256) mx = fmaxf(mx, sL[g]);
    red[t]=mx; __syncthreads();
    for (int s=128;s>0;s>>=1){ if(t<s) red[t]=fmaxf(red[t],red[t+s]); __syncthreads(); }
    mx = red[0]; __syncthreads();
    float sm = 0.f;
    for (int g=t; g<GS; g+=256) sm += __expf(sL[g]-mx);
    red[t]=sm; __syncthreads();
    for (int s=128;s>0;s>>=1){ if(t<s) red[t]+=red[t+s]; __syncthreads(); }
    if (t==0){
        float lse = mx + __logf(red[0]);
        atomicAdd(&out[BS*12 + b], sL[action] - lse);
    }
}

// ----------------------------------------------------------------
extern "C" void kernel_launch(void* const* d_in, const int* in_sizes, int n_in,
                              void* d_out, int out_size, void* d_ws, size_t ws_size,
                              hipStream_t stream)
{
    const float* h            = (const float*)d_in[0];
    const int*   rec          = (const int*)  d_in[1];
    /* d_in[2] = context2, unused by reference */
    const int*   vtime        = (const int*)  d_in[3];
    const int*   last_action  = (const int*)  d_in[4];
    const int*   fixed_action = (const int*)  d_in[5];
    const float* WK1=(const float*)d_in[6],  *WK2=(const float*)d_in[7];
    const float* WK3=(const float*)d_in[8],  *WK4=(const float*)d_in[9];
    const float* WQ1=(const float*)d_in[10], *WQ2=(const float*)d_in[11];
    const float* WQ3=(const float*)d_in[12], *WQ4=(const float*)d_in[13];
    const float* W_init=(const float*)d_in[14];
    const float* b_init=(const float*)d_in[15];
    const float* V1=(const float*)d_in[16], *V2=(const float*)d_in[17];
    const float* init_query=(const float*)d_in[18];
    const float* Wih1=(const float*)d_in[19], *Whh1=(const float*)d_in[20];
    const float* bih1=(const float*)d_in[21], *bhh1=(const float*)d_in[22];
    const float* Wih2=(const float*)d_in[23], *Whh2=(const float*)d_in[24];
    const float* bih2=(const float*)d_in[25], *bhh2=(const float*)d_in[26];
    float* out = (float*)d_out;

    char* ws = (char*)d_ws;
    size_t off = 0;
    auto alloc = [&](size_t bytes)->char*{
        char* p = ws + off; off += (bytes + 255) & ~(size_t)255; return p;
    };
    bf16_t* Mb     = (bf16_t*)alloc((size_t)8*BS*E*E*sizeof(bf16_t));   // 33.5 MB
    float*  raw4   = (float*) alloc((size_t)KMAXI*BS*GS*sizeof(float)); // 4.1 MB
    float*  add_buf= (float*) alloc((size_t)8*BS*E*sizeof(float));
    float*  hpart  = (float*) alloc((size_t)BS*16*E*sizeof(float));
    int*    sc     = (int*)   alloc((size_t)BS*SC_STRIDE*sizeof(int));
    (void)in_sizes; (void)n_in; (void)out_size; (void)ws_size;

    hipLaunchKernelGGL(k_hmean, dim3(BS,17), dim3(256), 0, stream,
                       h, hpart, rec, vtime, last_action, fixed_action, sc, out);
    hipLaunchKernelGGL(k_gru4, dim3(BS,2), dim3(384), 0, stream,
                       hpart, W_init, b_init, init_query, h, sc,
                       Wih1,Whh1,bih1,bhh1, Wih2,Whh2,bih2,bhh2,
                       WQ1,WQ2,WQ3,WQ4, WK1,WK2,WK3,WK4, add_buf, Mb);
    hipLaunchKernelGGL(k_scores, dim3(BS,8), dim3(256), 0, stream,
                       h, Mb, add_buf, V1, V2, raw4);
    hipLaunchKernelGGL(k_ll, dim3(BS, KMAXI), dim3(256), 0, stream,
                       raw4, sc, vtime, last_action, out);
}

// Round 6
// 431.193 us; speedup vs baseline: 1.1737x; 1.0708x over previous
//
#include <hip/hip_runtime.h>
#include <math.h>

#define BS 128
#define GS 2000
#define E  128
#define KMAXI 4
#define CLIPV 10.0f
#define NEGV  -1.0e30f

typedef __bf16 bf16_t;
typedef __bf16 bf16x8 __attribute__((ext_vector_type(8)));
typedef float fx4 __attribute__((ext_vector_type(4)));
typedef float fx2 __attribute__((ext_vector_type(2)));

__device__ __forceinline__ float fast_sigmoid(float x){ return 1.0f/(1.0f+__expf(-x)); }
__device__ __forceinline__ float fast_tanhf(float x){
    float e = __expf(2.0f*x);
    return 1.0f - 2.0f/(e + 1.0f);
}
// Padé(3,2) tanh clamped at |x|=3 — epilogue only.
__device__ __forceinline__ float pade_tanh(float x){
    float t = __builtin_amdgcn_fmed3f(x, -3.0f, 3.0f);
    float r = t*t;
    float num = t*(27.0f + r);
    float den = fmaf(9.0f, r, 27.0f);
    return num * __builtin_amdgcn_rcpf(den);
}
// Packed odd-poly tanh, clamp at |x|=3 (max err ~0.036; rcp-free, pk_fma-friendly).
__device__ __forceinline__ fx2 tanh2_poly(fx2 x){
    fx2 t;
    t.x = __builtin_amdgcn_fmed3f(x.x, -3.0f, 3.0f);
    t.y = __builtin_amdgcn_fmed3f(x.y, -3.0f, 3.0f);
    fx2 r = t*t;
    fx2 q = r*(-0.0015650f) + 0.03172875f;
    q = q*r + (-0.23082094f);
    q = q*r + 0.979947f;
    return t*q;
}
// diff known to lie in (-GS, GS): python-mod without integer divide
__device__ __forceinline__ int pymod_s(int a){ return a < 0 ? a + GS : a; }

// global -> LDS direct DMA, 16B per lane. lds dest must be base + lane*16 (m97/m104).
__device__ __forceinline__ void load_lds16(const bf16_t* g, bf16_t* l){
    __builtin_amdgcn_global_load_lds(
        (const __attribute__((address_space(1))) void*)g,
        (__attribute__((address_space(3))) void*)l, 16, 0, 0);
}

// scalars layout per b (stride 64 ints): [0]=a0 ; per it at 8+it*8:
// +0 action, +1 old_stopped, +2 new_stopped, +3 allow, +4 vta, +5 row1, +6 row2
#define SC_STRIDE 64

// ---------------------------------------------------------------- h mean partials (+ traj on the extra y-slice)
__global__ __launch_bounds__(256) void k_hmean(
    const float* __restrict__ h, float* __restrict__ hpart,
    const int* __restrict__ rec, const int* __restrict__ vtime,
    const int* __restrict__ last_action, const int* __restrict__ fixed_action,
    int* __restrict__ sc, float* __restrict__ out)
{
    int b = blockIdx.x, p = blockIdx.y, tid = threadIdx.x;
    if (p == 16){
        // integer trajectory: one block (b==0), thread = batch element
        if (b != 0) return;
        int t = tid;
        if (t >= BS) return;
        int stopped = 1, nol = -1;
        int ai[4]={0,0,0,0}, kl[5]={0,0,0,0,0}, kr[4]={0,0,0,0};
        int a0 = 0;
        int* scb = sc + t*SC_STRIDE;
        for (int it=0; it<KMAXI; ++it){
            int action = (it==0) ? fixed_action[t*KMAXI]
                                 : (stopped ? ai[0] : fixed_action[t*KMAXI+it]);
            int old_stopped = stopped;
            if (it==0) a0 = action;
            int vta = (it==0) ? 0 : pymod_s(vtime[(size_t)t*GS+action] - vtime[(size_t)t*GS+a0]);
            int nna = rec[(size_t)t*GS+action];
            int eq  = (action == nol) ? 1 : 0;
            int new_stopped = (it==0) ? eq : (stopped | eq);
            int ai0 = (it==0) ? action : ai[0];
            int allow = (!new_stopped) && (nna == ai0);

            ai[it] = action;
            if (old_stopped)  kl[it] = action;
            if (!old_stopped) kr[(it+3)&3] = action;
            kl[it+1] = nna;
            if (new_stopped) kl[it] = kl[(it+4)%5];
            if (new_stopped) kr[it] = kr[(it+3)&3];

            int row1 = action;
            int i2 = pymod_s(nol);
            int row2 = old_stopped ? row1 : i2;

            int* s_it = scb + 8 + it*8;
            s_it[0]=action; s_it[1]=old_stopped; s_it[2]=new_stopped;
            s_it[3]=allow;  s_it[4]=vta; s_it[5]=row1; s_it[6]=row2;

            nol = new_stopped ? -1 : nna;
            stopped = new_stopped;
        }
        scb[0] = a0;
        if (!stopped) kr[3] = kl[4];
        out[BS*12 + t] = 0.0f;   // zero ll slot; k_ll atomicAdds later in-stream
        for (int j=0;j<4;++j) out[t*12+j]   = (float)ai[j];
        for (int j=0;j<4;++j) out[t*12+4+j] = (float)kl[j];
        for (int j=0;j<4;++j) out[t*12+8+j] = (float)kr[j];
        return;
    }
    int e4 = (tid & 31) * 4;
    int gsub = tid >> 5;
    float4 acc = {0.f,0.f,0.f,0.f};
    int g0 = p*125, g1 = g0+125;
    for (int g = g0 + gsub; g < g1; g += 8){
        float4 v = *(const float4*)(h + ((size_t)b*GS + g)*E + e4);
        acc.x += v.x; acc.y += v.y; acc.z += v.z; acc.w += v.w;
    }
    __shared__ float ps[8][E];
    *(float4*)(&ps[gsub][e4]) = acc;
    __syncthreads();
    if (tid < E){
        float s = 0.f;
        #pragma unroll
        for (int j=0;j<8;++j) s += ps[j][tid];
        hpart[(b*16+p)*E + tid] = s;
    }
}

__device__ __forceinline__ float dot32(const float* a, const float* __restrict__ w){
    const float4* a4=(const float4*)a; const float4* w4=(const float4*)w;
    float s=0.f;
    #pragma unroll 8
    for (int i=0;i<32;++i){ float4 x=a4[i], y=w4[i]; s += x.x*y.x + x.y*y.y + x.z*y.z + x.w*y.w; }
    return s;
}

// ---------------------------------------------------------------- all 4 GRU steps + fused M-build.
// 384 threads: one (ih,hh) gate-row pair per thread; 256 threads for the two projections;
// then all 384 build M[slot=s*2+rnn] from shared mv (kills k_mbuild + mul_buf).
__global__ __launch_bounds__(384) void k_gru4(
    const float* __restrict__ hpart, const float* __restrict__ W_init,
    const float* __restrict__ b_init, const float* __restrict__ init_query,
    const float* __restrict__ h, const int* __restrict__ sc,
    const float* __restrict__ Wih1, const float* __restrict__ Whh1,
    const float* __restrict__ bih1, const float* __restrict__ bhh1,
    const float* __restrict__ Wih2, const float* __restrict__ Whh2,
    const float* __restrict__ bih2, const float* __restrict__ bhh2,
    const float* __restrict__ WQ1, const float* __restrict__ WQ2,
    const float* __restrict__ WQ3, const float* __restrict__ WQ4,
    const float* __restrict__ WK1, const float* __restrict__ WK2,
    const float* __restrict__ WK3, const float* __restrict__ WK4,
    float* __restrict__ add_buf, bf16_t* __restrict__ Mb)
{
    int b = blockIdx.x, rnn = blockIdx.y, t = threadIdx.x;
    const float* Wih = rnn ? Wih2 : Wih1;
    const float* Whh = rnn ? Whh2 : Whh1;
    const float* bih = rnn ? bih2 : bih1;
    const float* bhh = rnn ? bhh2 : bhh1;
    const float* WQa = rnn ? WQ2 : WQ1;
    const float* WQm = rnn ? WQ4 : WQ3;
    const float* WKa = rnn ? WK2 : WK1;
    const float* WKm = rnn ? WK4 : WK3;

    __shared__ float xv[E], hv[E], mv[E];
    __shared__ float gi_s[3*E], gh_s[3*E];

    if (t < E){
        float s = 0.f;
        for (int p=0;p<16;++p) s += hpart[(b*16+p)*E + t];
        xv[t] = s * (1.0f/(float)GS);
    }
    __syncthreads();
    if (t < E) hv[t] = b_init[t] + dot32(xv, W_init + (size_t)t*E);
    __syncthreads();
    if (t < E) xv[t] = init_query[t];
    __syncthreads();

    for (int s=0; s<KMAXI; ++s){
        if (s>0){
            if (t < E){
                int row = sc[b*SC_STRIDE + 8 + (s-1)*8 + (rnn==0 ? 5 : 6)];
                xv[t] = h[((size_t)b*GS + row)*E + t];
            }
            __syncthreads();
        }
        // 384 rows: gi[t], gh[t]
        {
            float gi = bih[t] + dot32(xv, Wih + (size_t)t*E);
            float gh = bhh[t] + dot32(hv, Whh + (size_t)t*E);
            gi_s[t] = gi; gh_s[t] = gh;
        }
        __syncthreads();
        if (t < E){
            float r = fast_sigmoid(gi_s[t]     + gh_s[t]);
            float z = fast_sigmoid(gi_s[t+E]   + gh_s[t+E]);
            float n = fast_tanhf  (gi_s[t+2*E] + r*gh_s[t+2*E]);
            hv[t] = (1.f-z)*n + z*hv[t];
        }
        __syncthreads();
        int slot = s*2 + rnn;
        if (t < 2*E){
            int r = t & (E-1);
            const float* W = (t < E) ? WQa : WQm;
            float v = dot32(hv, W + (size_t)r*E);
            if (t < E) add_buf[(size_t)slot*BS*E + b*E + r] = v;
            else       mv[r] = v;
        }
        __syncthreads();
        // fused M-build: swizzled chunk layout (f,e8) -> chunk f*16 + (e8^(f&7))
        {
            bf16x8* outp = (bf16x8*)(Mb + ((size_t)slot*BS + b)*E*E);
            for (int u = t; u < 2048; u += 384){
                int f = u >> 4, e8 = u & 15;
                int e0 = e8*8;
                float mf = mv[f];
                float4 a0 = *(const float4*)(WKa + (size_t)f*E + e0);
                float4 a1 = *(const float4*)(WKa + (size_t)f*E + e0 + 4);
                float4 m0 = *(const float4*)(WKm + (size_t)f*E + e0);
                float4 m1 = *(const float4*)(WKm + (size_t)f*E + e0 + 4);
                bf16x8 o;
                o[0]=(bf16_t)(a0.x + m0.x*mf);
                o[1]=(bf16_t)(a0.y + m0.y*mf);
                o[2]=(bf16_t)(a0.z + m0.z*mf);
                o[3]=(bf16_t)(a0.w + m0.w*mf);
                o[4]=(bf16_t)(a1.x + m1.x*mf);
                o[5]=(bf16_t)(a1.y + m1.y*mf);
                o[6]=(bf16_t)(a1.z + m1.z*mf);
                o[7]=(bf16_t)(a1.w + m1.w*mf);
                outp[f*16 + (e8 ^ (f&7))] = o;
            }
        }
        __syncthreads();   // mv consumed before next step's projection rewrites it
    }
}

// ---------------------------------------------------------------- scores: r2 tile (128 rows, 2 sets),
// pair-staged LDS: both arms of an iteration DMA'd at once -> half the barriers/drains.
// 64KB LDS -> still exactly 2 blocks/CU (the proven sweet spot); (256,2) keeps VGPR ~116.
__global__ __launch_bounds__(256,2) void k_scores(
    const float* __restrict__ hf, const bf16_t* __restrict__ Mb,
    const float* __restrict__ add_buf,
    const float* __restrict__ V1, const float* __restrict__ V2,
    float* __restrict__ raw4)
{
    __shared__ bf16_t sM[2][E*E];    // 65536 B, linear DMA images (swizzled at source)
    int b = blockIdx.x, yc = blockIdx.y, tid = threadIdx.x;
    int wave = tid >> 6, lane = tid & 63;
    int qd = lane >> 4, cl = lane & 15;
    int gbase = yc*128 + wave*32;

    // V preload (per kernel): vv_r[arm][tf] = V[tf*16+cl]
    float vv_r[2][8];
    #pragma unroll
    for (int tf=0; tf<8; ++tf){
        vv_r[0][tf] = V1[tf*16+cl];
        vv_r[1][tf] = V2[tf*16+cl];
    }

    // A fragments: 2 sets x 16 g-rows, K=128 (32 VGPRs)
    bf16x8 afr[2][4];
    #pragma unroll
    for (int set=0; set<2; ++set){
        int grow = gbase + set*16 + cl;
        if (grow >= GS) grow = GS-1;
        const float* hrow = hf + ((size_t)b*GS + grow)*E;
        #pragma unroll
        for (int s=0;s<4;++s){
            const float* p = hrow + s*32 + qd*8;
            float4 u0 = *(const float4*)(p);
            float4 u1 = *(const float4*)(p+4);
            bf16x8 a;
            a[0]=(bf16_t)u0.x; a[1]=(bf16_t)u0.y; a[2]=(bf16_t)u0.z; a[3]=(bf16_t)u0.w;
            a[4]=(bf16_t)u1.x; a[5]=(bf16_t)u1.y; a[6]=(bf16_t)u1.z; a[7]=(bf16_t)u1.w;
            afr[set][s]=a;
        }
    }

    for (int it=0; it<KMAXI; ++it){
        // packed accumulators: [set][row-pair], accumulated across both arms
        fx2 s00={0.f,0.f}, s01={0.f,0.f}, s10={0.f,0.f}, s11={0.f,0.f};

        const bf16_t* G0 = Mb + ((size_t)(it*2+0)*BS + b)*E*E;
        const bf16_t* G1 = Mb + ((size_t)(it*2+1)*BS + b)*E*E;
        // per-it add preload for both arms (overlaps barrier+DMA latency)
        float av_r[2][8];
        #pragma unroll
        for (int tf=0; tf<8; ++tf){
            av_r[0][tf] = add_buf[(size_t)(it*2+0)*BS*E + b*E + tf*16+cl];
            av_r[1][tf] = add_buf[(size_t)(it*2+1)*BS*E + b*E + tf*16+cl];
        }

        __syncthreads();        // previous iteration's sM reads complete
        // DMA stage both arms: 16 x 1KB per wave, linear chunks
        #pragma unroll
        for (int j=0;j<8;++j){
            int c = wave*512 + j*64 + lane;
            load_lds16(G0 + (size_t)c*8, &sM[0][0] + (size_t)c*8);
            load_lds16(G1 + (size_t)c*8, &sM[1][0] + (size_t)c*8);
        }
        __syncthreads();        // vmcnt(0) drained by compiler before barrier

        #pragma unroll
        for (int arm=0; arm<2; ++arm){
            const bf16_t* sMc = &sM[arm][0];
            #pragma unroll
            for (int tf=0; tf<8; ++tf){
                int f = tf*16 + cl;
                bf16x8 b1[4];
                #pragma unroll
                for (int s=0;s<4;++s){
                    int e8 = s*4 + qd;
                    b1[s] = *(const bf16x8*)(sMc + ((size_t)(f*16 + (e8 ^ (f&7))))*8);
                }
                float av = av_r[arm][tf];
                // fold add[f] into the accumulator init (C layout: col=f for all 4 regs)
                fx4 a0 = {av,av,av,av};
                fx4 a1 = {av,av,av,av};
                #pragma unroll
                for (int s=0;s<4;++s){
                    a0 = __builtin_amdgcn_mfma_f32_16x16x32_bf16(afr[0][s], b1[s], a0, 0,0,0);
                    a1 = __builtin_amdgcn_mfma_f32_16x16x32_bf16(afr[1][s], b1[s], a1, 0,0,0);
                }
                fx2 vv2 = {vv_r[arm][tf], vv_r[arm][tf]};
                s00 += vv2 * tanh2_poly((fx2){a0[0], a0[1]});
                s01 += vv2 * tanh2_poly((fx2){a0[2], a0[3]});
                s10 += vv2 * tanh2_poly((fx2){a1[0], a1[1]});
                s11 += vv2 * tanh2_poly((fx2){a1[2], a1[3]});
            }
        }

        #pragma unroll
        for (int set=0;set<2;++set){
            fx2 pa = set ? s10 : s00;
            fx2 pb = set ? s11 : s01;
            float v[4] = {pa.x, pa.y, pb.x, pb.y};
            #pragma unroll
            for (int r=0;r<4;++r){
                float s = v[r];
                s += __shfl_xor(s, 1); s += __shfl_xor(s, 2);
                s += __shfl_xor(s, 4); s += __shfl_xor(s, 8);
                v[r] = s;
            }
            if (cl==0){
                int gi = gbase + set*16 + qd*4;
                if (gi+3 < GS){
                    float4 o;
                    o.x = CLIPV*pade_tanh(v[0]);
                    o.y = CLIPV*pade_tanh(v[1]);
                    o.z = CLIPV*pade_tanh(v[2]);
                    o.w = CLIPV*pade_tanh(v[3]);
                    *(float4*)(raw4 + ((size_t)it*BS + b)*GS + gi) = o;
                }
            }
        }
    }
}

// ---------------------------------------------------------------- ll: masked logsumexp, one (b,it) per block (r2-proven)
__global__ __launch_bounds__(256) void k_ll(
    const float* __restrict__ raw4, const int* __restrict__ sc,
    const int* __restrict__ vtime, const int* __restrict__ last_action,
    float* __restrict__ out)
{
    __shared__ float sL[GS];
    __shared__ float red[256];
    int b = blockIdx.x, it = blockIdx.y, t = threadIdx.x;
    const int* scb = sc + b*SC_STRIDE;
    const int* s_it = scb + 8 + it*8;
    int action = s_it[0], olds = s_it[1];
    if (it>0 && olds) return;          // contribution is exactly 0 — uniform per block
    int a0 = scb[0];
    int la = last_action[b];
    int vt0 = vtime[(size_t)b*GS + a0];
    int ap=0, nsp=0, alp=0, vtp=0, p = it-1;
    if (it>0){
        const int* s_p = scb + 8 + p*8;
        ap = s_p[0]; nsp = s_p[2]; alp = s_p[3]; vtp = s_p[4];
    }
    for (int g=t; g<GS; g+=256){
        float l = raw4[((size_t)it*BS + b)*GS + g];
        int m;
        if (it==0){
            m = (g==la);
        } else {
            int d = vtime[(size_t)b*GS+g] - vt0;
            if (d < 0) d += GS;
            m = (d <= vtp) ? 1 : 0;
            if (p==0 && d > GS-2) m = 1;
            if (nsp && g==ap)     m = 0;
            if (alp && g==a0)     m = 0;
        }
        sL[g] = m ? NEGV : l;
    }
    __syncthreads();
    float mx = -3.0e38f;
    for (int g=t; g<GS; g+=256) mx = fmaxf(mx, sL[g]);
    red[t]=mx; __syncthreads();
    for (int s=128;s>0;s>>=1){ if(t<s) red[t]=fmaxf(red[t],red[t+s]); __syncthreads(); }
    mx = red[0]; __syncthreads();
    float sm = 0.f;
    for (int g=t; g<GS; g+=256) sm += __expf(sL[g]-mx);
    red[t]=sm; __syncthreads();
    for (int s=128;s>0;s>>=1){ if(t<s) red[t]+=red[t+s]; __syncthreads(); }
    if (t==0){
        float lse = mx + __logf(red[0]);
        atomicAdd(&out[BS*12 + b], sL[action] - lse);
    }
}

// ----------------------------------------------------------------
extern "C" void kernel_launch(void* const* d_in, const int* in_sizes, int n_in,
                              void* d_out, int out_size, void* d_ws, size_t ws_size,
                              hipStream_t stream)
{
    const float* h            = (const float*)d_in[0];
    const int*   rec          = (const int*)  d_in[1];
    /* d_in[2] = context2, unused by reference */
    const int*   vtime        = (const int*)  d_in[3];
    const int*   last_action  = (const int*)  d_in[4];
    const int*   fixed_action = (const int*)  d_in[5];
    const float* WK1=(const float*)d_in[6],  *WK2=(const float*)d_in[7];
    const float* WK3=(const float*)d_in[8],  *WK4=(const float*)d_in[9];
    const float* WQ1=(const float*)d_in[10], *WQ2=(const float*)d_in[11];
    const float* WQ3=(const float*)d_in[12], *WQ4=(const float*)d_in[13];
    const float* W_init=(const float*)d_in[14];
    const float* b_init=(const float*)d_in[15];
    const float* V1=(const float*)d_in[16], *V2=(const float*)d_in[17];
    const float* init_query=(const float*)d_in[18];
    const float* Wih1=(const float*)d_in[19], *Whh1=(const float*)d_in[20];
    const float* bih1=(const float*)d_in[21], *bhh1=(const float*)d_in[22];
    const float* Wih2=(const float*)d_in[23], *Whh2=(const float*)d_in[24];
    const float* bih2=(const float*)d_in[25], *bhh2=(const float*)d_in[26];
    float* out = (float*)d_out;

    char* ws = (char*)d_ws;
    size_t off = 0;
    auto alloc = [&](size_t bytes)->char*{
        char* p = ws + off; off += (bytes + 255) & ~(size_t)255; return p;
    };
    bf16_t* Mb     = (bf16_t*)alloc((size_t)8*BS*E*E*sizeof(bf16_t));   // 33.5 MB
    float*  raw4   = (float*) alloc((size_t)KMAXI*BS*GS*sizeof(float)); // 4.1 MB
    float*  add_buf= (float*) alloc((size_t)8*BS*E*sizeof(float));
    float*  hpart  = (float*) alloc((size_t)BS*16*E*sizeof(float));
    int*    sc     = (int*)   alloc((size_t)BS*SC_STRIDE*sizeof(int));
    (void)in_sizes; (void)n_in; (void)out_size; (void)ws_size;

    hipLaunchKernelGGL(k_hmean, dim3(BS,17), dim3(256), 0, stream,
                       h, hpart, rec, vtime, last_action, fixed_action, sc, out);
    hipLaunchKernelGGL(k_gru4, dim3(BS,2), dim3(384), 0, stream,
                       hpart, W_init, b_init, init_query, h, sc,
                       Wih1,Whh1,bih1,bhh1, Wih2,Whh2,bih2,bhh2,
                       WQ1,WQ2,WQ3,WQ4, WK1,WK2,WK3,WK4, add_buf, Mb);
    hipLaunchKernelGGL(k_scores, dim3(BS,16), dim3(256), 0, stream,
                       h, Mb, add_buf, V1, V2, raw4);
    hipLaunchKernelGGL(k_ll, dim3(BS, KMAXI), dim3(256), 0, stream,
                       raw4, sc, vtime, last_action, out);
}